// Round 18
// baseline (140.496 us; speedup 1.0000x reference)
//
#include <hip/hip_runtime.h>
#include <hip/hip_bf16.h>

#define NN 50000
#define EE 800000
#define HC 128
#define GG 64

#define NBLK 256
#define CHUNK (EE / NBLK)          // 3125
#define NBUCK ((NN + 63) >> 6)     // 782 coarse buckets (64 nodes each)
#define NTOT (NBUCK * NBLK)        // 200192 count-matrix entries
#define NSB ((NTOT + 1023) / 1024) // 196 scan blocks
#define ECAP 2048                  // per-bucket edge capacity (mean ~1023, sd ~32)

typedef __attribute__((ext_vector_type(8))) short bf16x8;
typedef __attribute__((ext_vector_type(4))) float f32x4;
typedef _Float16 hv2 __attribute__((ext_vector_type(2)));

// ---- DPP 16-lane row reduction (fusable v_add_f32_dpp form: old=0, bound_ctrl=1) ----
__device__ __forceinline__ float dpp4_redrow(float t) {
  t += __int_as_float(__builtin_amdgcn_update_dpp(0, __float_as_int(t), 0x111, 0xf, 0xf, true));
  t += __int_as_float(__builtin_amdgcn_update_dpp(0, __float_as_int(t), 0x112, 0xf, 0xf, true));
  t += __int_as_float(__builtin_amdgcn_update_dpp(0, __float_as_int(t), 0x114, 0xf, 0xf, true));
  t += __int_as_float(__builtin_amdgcn_update_dpp(0, __float_as_int(t), 0x118, 0xf, 0xf, true));
  return t;
}
// broadcast lane15 of each 16-lane group (BitMode: and=0x10, or=0x0F)
__device__ __forceinline__ float bcast15(float t) {
  return __int_as_float(__builtin_amdgcn_ds_swizzle(__float_as_int(t), 0x1F0));
}

__device__ __forceinline__ unsigned pkbf(float lo, float hi) {
  __hip_bfloat162 h = __float22bfloat162_rn(float2{lo, hi});  // x -> low 16 bits
  return *reinterpret_cast<unsigned*>(&h);
}
__device__ __forceinline__ unsigned pkhf(float lo, float hi) {
  hv2 h; h.x = (_Float16)lo; h.y = (_Float16)hi;
  return __builtin_bit_cast(unsigned, h);
}

// ---------------- W transpose+convert ----------------
__global__ __launch_bounds__(128) void prep_w(const float* __restrict__ Wl,
                                              const float* __restrict__ Wr,
                                              short* __restrict__ Wtb) {
  int c = blockIdx.x;           // 0..255
  int k = threadIdx.x;          // 0..127
  const float* W = (c < 128) ? Wl : Wr;
  float v = W[k * 128 + (c & 127)];
  Wtb[c * 128 + k] = (short)(pkbf(v, 0.f) & 0xFFFF);
}

// ---------------- GEMM (MFMA bf16) + fused coarse histogram ----------------
__global__ __launch_bounds__(256) void gemm_xw(
    const float* __restrict__ x, const short* __restrict__ Wtb,
    _Float16* __restrict__ xlh, _Float16* __restrict__ xrh,
    const int* __restrict__ ei, int* __restrict__ H2T)
{
  __shared__ short xs[128 * 136];
  __shared__ int h[NBUCK];
  const int t = threadIdx.x;
  const int rowbase = blockIdx.x * 128;
#pragma unroll
  for (int i = 0; i < 16; ++i) {
    int fi = i * 256 + t;            // 4096 float4 per tile
    int row = fi >> 5, k4 = fi & 31;
    int ar = rowbase + row; if (ar >= NN) ar = NN - 1;
    float4 v = *(const float4*)(x + (size_t)ar * 128 + k4 * 4);
    uint2 p = { pkbf(v.x, v.y), pkbf(v.z, v.w) };
    *(uint2*)&xs[row * 136 + k4 * 4] = p;
  }
  __syncthreads();
  const int w = t >> 6, l = t & 63;
  const int lo16 = l & 15, hi = l >> 4;
  f32x4 accL[2][8], accR[2][8];
#pragma unroll
  for (int rf = 0; rf < 2; ++rf)
#pragma unroll
    for (int cf = 0; cf < 8; ++cf) {
      accL[rf][cf] = f32x4{0.f, 0.f, 0.f, 0.f};
      accR[rf][cf] = f32x4{0.f, 0.f, 0.f, 0.f};
    }

  const short* asrc0 = &xs[(w * 32 + lo16) * 136 + hi * 8];
  const short* asrc1 = asrc0 + 16 * 136;
#pragma unroll
  for (int ks = 0; ks < 4; ++ks) {
    bf16x8 a0 = *(const bf16x8*)(asrc0 + ks * 32);
    bf16x8 a1 = *(const bf16x8*)(asrc1 + ks * 32);
#pragma unroll
    for (int cf = 0; cf < 8; ++cf) {
      const short* bp = &Wtb[(cf * 16 + lo16) * 128 + ks * 32 + hi * 8];
      bf16x8 bL = *(const bf16x8*)bp;
      bf16x8 bR = *(const bf16x8*)(bp + 128 * 128);
      accL[0][cf] = __builtin_amdgcn_mfma_f32_16x16x32_bf16(a0, bL, accL[0][cf], 0, 0, 0);
      accL[1][cf] = __builtin_amdgcn_mfma_f32_16x16x32_bf16(a1, bL, accL[1][cf], 0, 0, 0);
      accR[0][cf] = __builtin_amdgcn_mfma_f32_16x16x32_bf16(a0, bR, accR[0][cf], 0, 0, 0);
      accR[1][cf] = __builtin_amdgcn_mfma_f32_16x16x32_bf16(a1, bR, accR[1][cf], 0, 0, 0);
    }
  }
  // D layout: col=l&15, row=(l>>4)*4+reg
#pragma unroll
  for (int rf = 0; rf < 2; ++rf)
#pragma unroll
    for (int cf = 0; cf < 8; ++cf)
#pragma unroll
      for (int r = 0; r < 4; ++r) {
        int row = rowbase + w * 32 + rf * 16 + hi * 4 + r;
        if (row < NN) {
          int col = cf * 16 + lo16;
          xlh[(size_t)row * 128 + col] = (_Float16)accL[rf][cf][r];
          xrh[(size_t)row * 128 + col] = (_Float16)accR[rf][cf][r];
        }
      }
  // ---- fused histogram (blocks 0..NBLK-1) ----
  int blk = blockIdx.x;
  if (blk < NBLK) {
    for (int b = t; b < NBUCK; b += 256) h[b] = 0;
    __syncthreads();
    int e0 = blk * CHUNK;
    for (int i = t; i < CHUNK; i += 256) {
      int d = ei[EE + e0 + i];
      atomicAdd(&h[d >> 6], 1);      // LDS atomic
    }
    __syncthreads();
    for (int b = t; b < NBUCK; b += 256) H2T[b * NBLK + blk] = h[b];
  }
}

// K2: coalesced exclusive scan of the bucket-major count array; bsum[blk] = block total.
__global__ __launch_bounds__(256) void scanA(const int* __restrict__ H2T,
                                             int* __restrict__ PS, int* __restrict__ bsum) {
  __shared__ int tmp[256];
  int t = threadIdx.x;
  int base = blockIdx.x * 1024 + t * 4;
  int4 v = {0, 0, 0, 0};
  if (base < NTOT) v = *(const int4*)&H2T[base];   // NTOT % 4 == 0
  int local = v.x + v.y + v.z + v.w;
  tmp[t] = local; __syncthreads();
  for (int off = 1; off < 256; off <<= 1) {
    int xv = (t >= off) ? tmp[t - off] : 0; __syncthreads();
    tmp[t] += xv; __syncthreads();
  }
  int excl = tmp[t] - local;
  if (base < NTOT) {
    int4 o;
    o.x = excl; excl += v.x;
    o.y = excl; excl += v.y;
    o.z = excl; excl += v.z;
    o.w = excl;
    *(int4*)&PS[base] = o;
  }
  if (t == 255) bsum[blockIdx.x] = tmp[255];
}

// K3: scatter into per-(bucket,block) sequential runs; pack src|fine<<16 (inline bsum scan).
__global__ __launch_bounds__(256) void scatter_coarse(const int* __restrict__ ei,
                                                      const int* __restrict__ PS,
                                                      const int* __restrict__ bsum,
                                                      int* __restrict__ ec) {
  __shared__ int colbase[NBUCK];
  __shared__ int cur[NBUCK];
  __shared__ int sb[NSB];
  __shared__ int stmp[256];
  int t = threadIdx.x, blk = blockIdx.x;
  int v = (t < NSB) ? bsum[t] : 0;
  stmp[t] = v; __syncthreads();
  for (int off = 1; off < 256; off <<= 1) {
    int xv = (t >= off) ? stmp[t - off] : 0; __syncthreads();
    stmp[t] += xv; __syncthreads();
  }
  if (t < NSB) sb[t] = stmp[t] - v;
  __syncthreads();
  for (int b = t; b < NBUCK; b += 256) {
    int L = b * NBLK + blk;
    colbase[b] = PS[L] + sb[L >> 10];
    cur[b] = 0;
  }
  __syncthreads();
  int e0 = blk * CHUNK;
  for (int i = t; i < CHUNK; i += 256) {
    int d = ei[EE + e0 + i], s = ei[e0 + i];
    int b = d >> 6;
    int r = atomicAdd(&cur[b], 1);  // LDS atomic
    ec[colbase[b] + r] = s | ((d & 63) << 16);
  }
}

// process M staged edges (stage-split: logits, exps, accumulate)
template<int M>
__device__ __forceinline__ void procM(const unsigned* wv, hv2 att2, hv2 xr2,
                                      float& s, float& a0, float& a1) {
  float tb[M];
#pragma unroll
  for (int i = 0; i < M; ++i) {
    hv2 v = __builtin_bit_cast(hv2, wv[i]);
    hv2 y = v + xr2;
    hv2 lr = __builtin_elementwise_max(y, y * (_Float16)0.2f);
    float td = __builtin_amdgcn_fdot2(lr, att2, 0.f, false);
    tb[i] = bcast15(dpp4_redrow(td));
  }
  float p[M];
#pragma unroll
  for (int i = 0; i < M; ++i) p[i] = __builtin_amdgcn_exp2f(tb[i]);
#pragma unroll
  for (int i = 0; i < M; ++i) {
    hv2 v = __builtin_bit_cast(hv2, wv[i]);
    s += p[i];
    a0 = fmaf(p[i], (float)v.x, a0);
    a1 = fmaf(p[i], (float)v.y, a1);
  }
}

// ---------------- fused fine-sort + aggregation: 782 blocks x 1024 threads (16 waves) ----------------
// phase 1: fine_sort's bucket sort at 4x staging parallelism; phase 2: 16 waves x ~4 nodes each
// (68 edge-visits/wave == the proven gat_agg per-wave workload; 2 blocks/CU = 32 waves/CU).
__global__ __launch_bounds__(1024) void gat_fused(
    const unsigned* __restrict__ xlu, const unsigned* __restrict__ xru,
    const int* __restrict__ PS, const int* __restrict__ bsum,
    const int* __restrict__ ec, const float* __restrict__ att,
    const float* __restrict__ bias, unsigned* __restrict__ outh)
{
  __shared__ int lbuf[ECAP];
  __shared__ int outb[ECAP + 64];
  __shared__ int fh[64], sexcl[65], cur2[64];
  __shared__ int sb[NSB];
  __shared__ int stmp[256];
  int t = threadIdx.x, b = blockIdx.x;
  // inline exclusive scan of bsum (196 entries) on the first 256 threads
  if (t < 256) {
    int v = (t < NSB) ? bsum[t] : 0;
    stmp[t] = v;
  }
  __syncthreads();
  if (t < 256) {
    for (int off = 1; off < 256; off <<= 1) {
      int xv = (t >= off) ? stmp[t - off] : 0; __syncthreads();
      stmp[t] += xv; __syncthreads();
    }
    if (t < NSB) sb[t] = stmp[t] - ((t < NSB) ? bsum[t] : 0);
  } else {
    for (int off = 1; off < 256; off <<= 1) { __syncthreads(); __syncthreads(); }
  }
  __syncthreads();
  int L0 = b * NBLK;
  int start = PS[L0] + sb[L0 >> 10];
  int end = (b + 1 < NBUCK) ? PS[L0 + NBLK] + sb[(L0 + NBLK) >> 10] : EE;
  int node0 = b << 6;
  int nl = NN - node0; if (nl > 64) nl = 64;
  int cnt = end - start; if (cnt > ECAP) cnt = ECAP;
  if (t < 64) { fh[t] = 0; cur2[t] = 0; }
  __syncthreads();
  for (int i = t; i < cnt; i += 1024) {
    int p = ec[start + i];
    lbuf[i] = p;
    atomicAdd(&fh[(p >> 16) & 63], 1);
  }
  __syncthreads();
  if (t < 64) {   // wave 0: inclusive shfl-scan of 64 bins (+1 self-loop per live node)
    int val = fh[t] + (t < nl ? 1 : 0);
    int w = val;
    for (int off = 1; off < 64; off <<= 1) {
      int u = __shfl_up(w, off);
      if (t >= off) w += u;
    }
    sexcl[t] = w - val;
    if (t == 63) sexcl[64] = w;
  }
  __syncthreads();
  if (t < nl) {
    int r = atomicAdd(&cur2[t], 1);
    outb[sexcl[t] + r] = node0 + t;              // self-loop src = node itself
  }
  for (int i = t; i < cnt; i += 1024) {
    int p = lbuf[i];
    int f = (p >> 16) & 63;
    int r = atomicAdd(&cur2[f], 1);
    outb[sexcl[f] + r] = p & 0xFFFF;             // src < 65536 (NN = 50000)
  }
  __syncthreads();

  // ---- phase 2: aggregation, 16 waves x (nl/16) nodes ----
  int wid = t >> 6, lane = t & 63;
  float2 at2 = ((const float2*)att)[lane];
  const float LOG2E = 1.4426950408889634f;
  hv2 att2;
  att2.x = (_Float16)(at2.x * LOG2E);
  att2.y = (_Float16)(at2.y * LOG2E);
  float2 bi = ((const float2*)bias)[lane];

  for (int ni = wid; ni < nl; ni += 16) {
    int n = node0 + ni;
    hv2 xr2 = __builtin_bit_cast(hv2, xru[n * 64 + lane]);
    float s = 0.f, a0 = 0.f, a1 = 0.f;
    int jbeg = sexcl[ni], jend = sexcl[ni + 1];
    for (int j0 = jbeg; j0 < jend; j0 += 64) {
      int cnt2 = jend - j0; if (cnt2 > 64) cnt2 = 64;
      int sj = outb[j0 + (lane < cnt2 ? lane : cnt2 - 1)];
      int base = 0;
      if (cnt2 >= 8) {
        unsigned cur[8];
#pragma unroll
        for (int i = 0; i < 8; ++i)
          cur[i] = xlu[__builtin_amdgcn_readlane(sj, i) * 64 + lane];
        for (; base + 16 <= cnt2; base += 8) {
          unsigned nxt[8];
#pragma unroll
          for (int i = 0; i < 8; ++i)   // prefetch batch k+1 before computing batch k
            nxt[i] = xlu[__builtin_amdgcn_readlane(sj, base + 8 + i) * 64 + lane];
          procM<8>(cur, att2, xr2, s, a0, a1);
#pragma unroll
          for (int i = 0; i < 8; ++i) cur[i] = nxt[i];
        }
        procM<8>(cur, att2, xr2, s, a0, a1);
        base += 8;
      }
      int rem = cnt2 - base;   // 0..7, wave-uniform
      if (rem) {
        unsigned wv[8];
#pragma unroll
        for (int i = 0; i < 8; ++i)
          if (i < rem) wv[i] = xlu[__builtin_amdgcn_readlane(sj, base + i) * 64 + lane];
        switch (rem) {
          case 1: procM<1>(wv, att2, xr2, s, a0, a1); break;
          case 2: procM<2>(wv, att2, xr2, s, a0, a1); break;
          case 3: procM<3>(wv, att2, xr2, s, a0, a1); break;
          case 4: procM<4>(wv, att2, xr2, s, a0, a1); break;
          case 5: procM<5>(wv, att2, xr2, s, a0, a1); break;
          case 6: procM<6>(wv, att2, xr2, s, a0, a1); break;
          default: procM<7>(wv, att2, xr2, s, a0, a1); break;
        }
      }
    }
    float inv = 1.f / s;
    float ox = fmaxf(fmaf(a0, inv, bi.x), 0.f);
    float oy = fmaxf(fmaf(a1, inv, bi.y), 0.f);
    outh[(size_t)n * 64 + lane] = pkhf(ox, oy);
  }
}

// ---------------- fused pooling + MLP: one block per graph, 1024 threads, packed-f16 input ----------------
__global__ __launch_bounds__(1024) void pool_mlp(const unsigned* __restrict__ outh,
                                                 const int* __restrict__ batch,
                                                 const float* __restrict__ W,
                                                 const float* __restrict__ bm,
                                                 float* __restrict__ out) {
  __shared__ float pm0[16][64];
  __shared__ float pm1[16][64];
  __shared__ float p[128];
  __shared__ float acc8[8][128];
  int g = blockIdx.x, t = threadIdx.x;
  int a = 0, bnd = NN;
  while (a < bnd) { int m = (a + bnd) >> 1; if (batch[m] < g) a = m + 1; else bnd = m; }
  int lo = a;
  bnd = NN;
  while (a < bnd) { int m = (a + bnd) >> 1; if (batch[m] < g + 1) a = m + 1; else bnd = m; }
  int hi = a;
  int c2 = t & 63, q16 = t >> 6;      // 16-deep row groups
  float m0 = 0.f, m1 = 0.f;           // relu outputs >= 0
  for (int n = lo + q16; n < hi; n += 16) {
    hv2 v = __builtin_bit_cast(hv2, outh[(size_t)n * 64 + c2]);
    m0 = fmaxf(m0, (float)v.x);
    m1 = fmaxf(m1, (float)v.y);
  }
  pm0[q16][c2] = m0;
  pm1[q16][c2] = m1;
  __syncthreads();
  if (t < 64) {
    float r0 = pm0[0][t], r1 = pm1[0][t];
#pragma unroll
    for (int i = 1; i < 16; ++i) {
      r0 = fmaxf(r0, pm0[i][t]);
      r1 = fmaxf(r1, pm1[i][t]);
    }
    p[2 * t] = r0;
    p[2 * t + 1] = r1;
  }
  __syncthreads();
  int c = t & 127, q = t >> 7;
  float acc = 0.f;
#pragma unroll
  for (int kk = 0; kk < 16; ++kk) {
    int k = q * 16 + kk;
    acc = fmaf(p[k], W[k * 128 + c], acc);
  }
  acc8[q][c] = acc;
  __syncthreads();
  if (q == 0) {
    float sum = bm[c];
#pragma unroll
    for (int i = 0; i < 8; ++i) sum += acc8[i][c];
    out[g * 128 + c] = fmaxf(sum, 0.f);
  }
}

extern "C" void kernel_launch(void* const* d_in, const int* in_sizes, int n_in,
                              void* d_out, int out_size, void* d_ws, size_t ws_size,
                              hipStream_t stream) {
  const float* x    = (const float*)d_in[0];
  const int*   ei   = (const int*)d_in[1];
  const int*   batch= (const int*)d_in[2];
  const float* Wl   = (const float*)d_in[4];
  const float* Wr   = (const float*)d_in[5];
  const float* att  = (const float*)d_in[6];
  const float* bias = (const float*)d_in[7];
  const float* Wm   = (const float*)d_in[8];
  const float* bm   = (const float*)d_in[9];

  char* ws = (char*)d_ws;
  size_t off = 0;
  auto alloc = [&](size_t bytes) { void* p = ws + off; off += (bytes + 255) & ~size_t(255); return p; };
  unsigned* xlu  = (unsigned*)alloc((size_t)NN * 64 * 4);   // f16-packed xl (12.8 MB)
  unsigned* xru  = (unsigned*)alloc((size_t)NN * 64 * 4);   // f16-packed xr (12.8 MB)
  unsigned* outh = (unsigned*)alloc((size_t)NN * 64 * 4);   // f16-packed conv output
  int*   H2T     = (int*)alloc((size_t)NTOT * 4);           // 800 KB bucket-major counts
  int*   PS      = (int*)alloc((size_t)NTOT * 4);           // 800 KB scanned positions
  int*   ec      = (int*)alloc((size_t)EE * 4);             // 3.2 MB coarse-sorted edges
  int*   bsum    = (int*)alloc(NSB * 4);
  short* Wtb     = (short*)alloc((size_t)256 * 128 * 2);    // bf16 W^T [col][k]

  prep_w<<<256, 128, 0, stream>>>(Wl, Wr, Wtb);
  gemm_xw<<<(NN + 127) / 128, 256, 0, stream>>>(x, Wtb, (_Float16*)xlu, (_Float16*)xru, ei, H2T);
  scanA<<<NSB, 256, 0, stream>>>(H2T, PS, bsum);
  scatter_coarse<<<NBLK, 256, 0, stream>>>(ei, PS, bsum, ec);
  gat_fused<<<NBUCK, 1024, 0, stream>>>(xlu, xru, PS, bsum, ec, att, bias, outh);
  pool_mlp<<<GG, 1024, 0, stream>>>(outh, batch, Wm, bm, (float*)d_out);
}

// Round 19
// 128.268 us; speedup vs baseline: 1.0953x; 1.0953x over previous
//
#include <hip/hip_runtime.h>
#include <hip/hip_bf16.h>

#define NN 50000
#define EE 800000
#define HC 128
#define GG 64

#define NBLK 256
#define CHUNK (EE / NBLK)          // 3125
#define NBUCK ((NN + 63) >> 6)     // 782 coarse buckets (64 nodes each)
#define NTOT (NBUCK * NBLK)        // 200192 count-matrix entries
#define NSB ((NTOT + 1023) / 1024) // 196 scan blocks
#define ECAP 2048                  // per-bucket edge capacity (mean ~1023, sd ~32)

typedef __attribute__((ext_vector_type(8))) short bf16x8;
typedef __attribute__((ext_vector_type(4))) float f32x4;
typedef _Float16 hv2 __attribute__((ext_vector_type(2)));

// ---- DPP 16-lane row reduction (fusable v_add_f32_dpp form: old=0, bound_ctrl=1) ----
__device__ __forceinline__ float dpp4_redrow(float t) {
  t += __int_as_float(__builtin_amdgcn_update_dpp(0, __float_as_int(t), 0x111, 0xf, 0xf, true));
  t += __int_as_float(__builtin_amdgcn_update_dpp(0, __float_as_int(t), 0x112, 0xf, 0xf, true));
  t += __int_as_float(__builtin_amdgcn_update_dpp(0, __float_as_int(t), 0x114, 0xf, 0xf, true));
  t += __int_as_float(__builtin_amdgcn_update_dpp(0, __float_as_int(t), 0x118, 0xf, 0xf, true));
  return t;
}
// broadcast lane15 of each 16-lane group (BitMode: and=0x10, or=0x0F)
__device__ __forceinline__ float bcast15(float t) {
  return __int_as_float(__builtin_amdgcn_ds_swizzle(__float_as_int(t), 0x1F0));
}

__device__ __forceinline__ unsigned pkbf(float lo, float hi) {
  __hip_bfloat162 h = __float22bfloat162_rn(float2{lo, hi});  // x -> low 16 bits
  return *reinterpret_cast<unsigned*>(&h);
}
__device__ __forceinline__ unsigned pkhf(float lo, float hi) {
  hv2 h; h.x = (_Float16)lo; h.y = (_Float16)hi;
  return __builtin_bit_cast(unsigned, h);
}

// ---------------- W transpose+convert ----------------
__global__ __launch_bounds__(128) void prep_w(const float* __restrict__ Wl,
                                              const float* __restrict__ Wr,
                                              short* __restrict__ Wtb) {
  int c = blockIdx.x;           // 0..255
  int k = threadIdx.x;          // 0..127
  const float* W = (c < 128) ? Wl : Wr;
  float v = W[k * 128 + (c & 127)];
  Wtb[c * 128 + k] = (short)(pkbf(v, 0.f) & 0xFFFF);
}

// ---------------- GEMM (MFMA bf16) + fused coarse histogram ----------------
__global__ __launch_bounds__(256) void gemm_xw(
    const float* __restrict__ x, const short* __restrict__ Wtb,
    _Float16* __restrict__ xlh, _Float16* __restrict__ xrh,
    const int* __restrict__ ei, int* __restrict__ H2T)
{
  __shared__ short xs[128 * 136];
  __shared__ int h[NBUCK];
  const int t = threadIdx.x;
  const int rowbase = blockIdx.x * 128;
#pragma unroll
  for (int i = 0; i < 16; ++i) {
    int fi = i * 256 + t;            // 4096 float4 per tile
    int row = fi >> 5, k4 = fi & 31;
    int ar = rowbase + row; if (ar >= NN) ar = NN - 1;
    float4 v = *(const float4*)(x + (size_t)ar * 128 + k4 * 4);
    uint2 p = { pkbf(v.x, v.y), pkbf(v.z, v.w) };
    *(uint2*)&xs[row * 136 + k4 * 4] = p;
  }
  __syncthreads();
  const int w = t >> 6, l = t & 63;
  const int lo16 = l & 15, hi = l >> 4;
  f32x4 accL[2][8], accR[2][8];
#pragma unroll
  for (int rf = 0; rf < 2; ++rf)
#pragma unroll
    for (int cf = 0; cf < 8; ++cf) {
      accL[rf][cf] = f32x4{0.f, 0.f, 0.f, 0.f};
      accR[rf][cf] = f32x4{0.f, 0.f, 0.f, 0.f};
    }

  const short* asrc0 = &xs[(w * 32 + lo16) * 136 + hi * 8];
  const short* asrc1 = asrc0 + 16 * 136;
#pragma unroll
  for (int ks = 0; ks < 4; ++ks) {
    bf16x8 a0 = *(const bf16x8*)(asrc0 + ks * 32);
    bf16x8 a1 = *(const bf16x8*)(asrc1 + ks * 32);
#pragma unroll
    for (int cf = 0; cf < 8; ++cf) {
      const short* bp = &Wtb[(cf * 16 + lo16) * 128 + ks * 32 + hi * 8];
      bf16x8 bL = *(const bf16x8*)bp;
      bf16x8 bR = *(const bf16x8*)(bp + 128 * 128);
      accL[0][cf] = __builtin_amdgcn_mfma_f32_16x16x32_bf16(a0, bL, accL[0][cf], 0, 0, 0);
      accL[1][cf] = __builtin_amdgcn_mfma_f32_16x16x32_bf16(a1, bL, accL[1][cf], 0, 0, 0);
      accR[0][cf] = __builtin_amdgcn_mfma_f32_16x16x32_bf16(a0, bR, accR[0][cf], 0, 0, 0);
      accR[1][cf] = __builtin_amdgcn_mfma_f32_16x16x32_bf16(a1, bR, accR[1][cf], 0, 0, 0);
    }
  }
  // D layout: col=l&15, row=(l>>4)*4+reg
#pragma unroll
  for (int rf = 0; rf < 2; ++rf)
#pragma unroll
    for (int cf = 0; cf < 8; ++cf)
#pragma unroll
      for (int r = 0; r < 4; ++r) {
        int row = rowbase + w * 32 + rf * 16 + hi * 4 + r;
        if (row < NN) {
          int col = cf * 16 + lo16;
          xlh[(size_t)row * 128 + col] = (_Float16)accL[rf][cf][r];
          xrh[(size_t)row * 128 + col] = (_Float16)accR[rf][cf][r];
        }
      }
  // ---- fused histogram (blocks 0..NBLK-1) ----
  int blk = blockIdx.x;
  if (blk < NBLK) {
    for (int b = t; b < NBUCK; b += 256) h[b] = 0;
    __syncthreads();
    int e0 = blk * CHUNK;
    for (int i = t; i < CHUNK; i += 256) {
      int d = ei[EE + e0 + i];
      atomicAdd(&h[d >> 6], 1);      // LDS atomic
    }
    __syncthreads();
    for (int b = t; b < NBUCK; b += 256) H2T[b * NBLK + blk] = h[b];
  }
}

// K2: coalesced exclusive scan of the bucket-major count array; bsum[blk] = block total.
__global__ __launch_bounds__(256) void scanA(const int* __restrict__ H2T,
                                             int* __restrict__ PS, int* __restrict__ bsum) {
  __shared__ int tmp[256];
  int t = threadIdx.x;
  int base = blockIdx.x * 1024 + t * 4;
  int4 v = {0, 0, 0, 0};
  if (base < NTOT) v = *(const int4*)&H2T[base];   // NTOT % 4 == 0
  int local = v.x + v.y + v.z + v.w;
  tmp[t] = local; __syncthreads();
  for (int off = 1; off < 256; off <<= 1) {
    int xv = (t >= off) ? tmp[t - off] : 0; __syncthreads();
    tmp[t] += xv; __syncthreads();
  }
  int excl = tmp[t] - local;
  if (base < NTOT) {
    int4 o;
    o.x = excl; excl += v.x;
    o.y = excl; excl += v.y;
    o.z = excl; excl += v.z;
    o.w = excl;
    *(int4*)&PS[base] = o;
  }
  if (t == 255) bsum[blockIdx.x] = tmp[255];
}

// K3: scatter into per-(bucket,block) sequential runs; pack src|fine<<16 (inline bsum scan).
// 512 threads: halves the per-block staging trip count.
__global__ __launch_bounds__(512) void scatter_coarse(const int* __restrict__ ei,
                                                      const int* __restrict__ PS,
                                                      const int* __restrict__ bsum,
                                                      int* __restrict__ ec) {
  __shared__ int colbase[NBUCK];
  __shared__ int cur[NBUCK];
  __shared__ int sb[NSB];
  __shared__ int stmp[512];
  int t = threadIdx.x, blk = blockIdx.x;
  int v = (t < NSB) ? bsum[t] : 0;
  stmp[t] = v; __syncthreads();
  for (int off = 1; off < 512; off <<= 1) {
    int xv = (t >= off) ? stmp[t - off] : 0; __syncthreads();
    stmp[t] += xv; __syncthreads();
  }
  if (t < NSB) sb[t] = stmp[t] - v;
  __syncthreads();
  for (int b = t; b < NBUCK; b += 512) {
    int L = b * NBLK + blk;
    colbase[b] = PS[L] + sb[L >> 10];
    cur[b] = 0;
  }
  __syncthreads();
  int e0 = blk * CHUNK;
  for (int i = t; i < CHUNK; i += 512) {
    int d = ei[EE + e0 + i], s = ei[e0 + i];
    int b = d >> 6;
    int r = atomicAdd(&cur[b], 1);  // LDS atomic
    ec[colbase[b] + r] = s | ((d & 63) << 16);
  }
}

// K4: per-bucket fine sort, inject self-loops, emit rs + coalesced csr (inline bsum scan).
// 512 threads: halves staging/emit trip counts.
__global__ __launch_bounds__(512) void fine_sort(const int* __restrict__ PS,
                                                 const int* __restrict__ bsum,
                                                 const int* __restrict__ ec,
                                                 int* __restrict__ rs, int* __restrict__ csr) {
  __shared__ int lbuf[ECAP];
  __shared__ int outb[ECAP + 64];
  __shared__ int fh[64], sexcl[65], cur2[64];
  __shared__ int sb[NSB];
  __shared__ int stmp[512];
  int t = threadIdx.x, b = blockIdx.x;
  int v = (t < NSB) ? bsum[t] : 0;
  stmp[t] = v; __syncthreads();
  for (int off = 1; off < 512; off <<= 1) {
    int xv = (t >= off) ? stmp[t - off] : 0; __syncthreads();
    stmp[t] += xv; __syncthreads();
  }
  if (t < NSB) sb[t] = stmp[t] - v;
  __syncthreads();
  int L0 = b * NBLK;
  int start = PS[L0] + sb[L0 >> 10];
  int end = (b + 1 < NBUCK) ? PS[L0 + NBLK] + sb[(L0 + NBLK) >> 10] : EE;
  int node0 = b << 6;
  int nl = NN - node0; if (nl > 64) nl = 64;
  int cnt = end - start; if (cnt > ECAP) cnt = ECAP;
  if (t < 64) { fh[t] = 0; cur2[t] = 0; }
  __syncthreads();
  for (int i = t; i < cnt; i += 512) {
    int p = ec[start + i];
    lbuf[i] = p;
    atomicAdd(&fh[(p >> 16) & 63], 1);
  }
  __syncthreads();
  if (t < 64) {   // wave 0: inclusive shfl-scan of 64 bins (+1 self-loop per live node)
    int val = fh[t] + (t < nl ? 1 : 0);
    int w = val;
    for (int off = 1; off < 64; off <<= 1) {
      int u = __shfl_up(w, off);
      if (t >= off) w += u;
    }
    sexcl[t] = w - val;
    if (t == 63) sexcl[64] = w;
  }
  __syncthreads();
  int base = start + node0;   // node0 == number of self-loops in earlier buckets
  if (t <= nl) rs[node0 + t] = base + sexcl[t];
  if (t < nl) {
    int r = atomicAdd(&cur2[t], 1);
    outb[sexcl[t] + r] = node0 + t;              // self-loop src = node itself
  }
  for (int i = t; i < cnt; i += 512) {
    int p = lbuf[i];
    int f = (p >> 16) & 63;
    int r = atomicAdd(&cur2[f], 1);
    outb[sexcl[f] + r] = p & 0xFFFF;             // src < 65536 (NN = 50000)
  }
  __syncthreads();
  int tot = cnt + nl;
  for (int i = t; i < tot; i += 512) csr[base + i] = outb[i];
}

// process M staged edges (stage-split: logits, exps, accumulate)
template<int M>
__device__ __forceinline__ void procM(const unsigned* wv, hv2 att2, hv2 xr2,
                                      float& s, float& a0, float& a1) {
  float tb[M];
#pragma unroll
  for (int i = 0; i < M; ++i) {
    hv2 v = __builtin_bit_cast(hv2, wv[i]);
    hv2 y = v + xr2;
    hv2 lr = __builtin_elementwise_max(y, y * (_Float16)0.2f);
    float td = __builtin_amdgcn_fdot2(lr, att2, 0.f, false);
    tb[i] = bcast15(dpp4_redrow(td));
  }
  float p[M];
#pragma unroll
  for (int i = 0; i < M; ++i) p[i] = __builtin_amdgcn_exp2f(tb[i]);
#pragma unroll
  for (int i = 0; i < M; ++i) {
    hv2 v = __builtin_bit_cast(hv2, wv[i]);
    s += p[i];
    a0 = fmaf(p[i], (float)v.x, a0);
    a1 = fmaf(p[i], (float)v.y, a1);
  }
}

// ---------------- main aggregation: one wave per node, 2-deep pipelined 8-edge batches ----------------
// output stored as packed f16 (u32/lane) to halve write+pool traffic
__global__ __launch_bounds__(256) void gat_agg(
    const unsigned* __restrict__ xlu, const unsigned* __restrict__ xru,
    const int* __restrict__ rs, const int* __restrict__ csr,
    const float* __restrict__ att, const float* __restrict__ bias,
    unsigned* __restrict__ outh)
{
  int wid = threadIdx.x >> 6, lane = threadIdx.x & 63;
  int n = blockIdx.x * 4 + wid;
  if (n >= NN) return;
  hv2 xr2 = __builtin_bit_cast(hv2, xru[n * 64 + lane]);
  float2 at2 = ((const float2*)att)[lane];
  const float LOG2E = 1.4426950408889634f;
  hv2 att2;
  att2.x = (_Float16)(at2.x * LOG2E);
  att2.y = (_Float16)(at2.y * LOG2E);
  float s = 0.f, a0 = 0.f, a1 = 0.f;

  int jbeg = rs[n], jend = rs[n + 1];
  for (int j0 = jbeg; j0 < jend; j0 += 64) {
    int cnt = jend - j0; if (cnt > 64) cnt = 64;
    int sj = csr[j0 + (lane < cnt ? lane : cnt - 1)];
    int base = 0;
    if (cnt >= 8) {
      unsigned cur[8];
#pragma unroll
      for (int i = 0; i < 8; ++i)
        cur[i] = xlu[__builtin_amdgcn_readlane(sj, i) * 64 + lane];
      for (; base + 16 <= cnt; base += 8) {
        unsigned nxt[8];
#pragma unroll
        for (int i = 0; i < 8; ++i)   // prefetch batch k+1 before computing batch k
          nxt[i] = xlu[__builtin_amdgcn_readlane(sj, base + 8 + i) * 64 + lane];
        procM<8>(cur, att2, xr2, s, a0, a1);
#pragma unroll
        for (int i = 0; i < 8; ++i) cur[i] = nxt[i];
      }
      procM<8>(cur, att2, xr2, s, a0, a1);
      base += 8;
    }
    int rem = cnt - base;   // 0..7, wave-uniform
    if (rem) {
      unsigned wv[8];
#pragma unroll
      for (int i = 0; i < 8; ++i)
        if (i < rem) wv[i] = xlu[__builtin_amdgcn_readlane(sj, base + i) * 64 + lane];
      switch (rem) {
        case 1: procM<1>(wv, att2, xr2, s, a0, a1); break;
        case 2: procM<2>(wv, att2, xr2, s, a0, a1); break;
        case 3: procM<3>(wv, att2, xr2, s, a0, a1); break;
        case 4: procM<4>(wv, att2, xr2, s, a0, a1); break;
        case 5: procM<5>(wv, att2, xr2, s, a0, a1); break;
        case 6: procM<6>(wv, att2, xr2, s, a0, a1); break;
        default: procM<7>(wv, att2, xr2, s, a0, a1); break;
      }
    }
  }
  float inv = 1.f / s;
  float2 bi = ((const float2*)bias)[lane];
  float ox = fmaxf(fmaf(a0, inv, bi.x), 0.f);
  float oy = fmaxf(fmaf(a1, inv, bi.y), 0.f);
  outh[(size_t)n * 64 + lane] = pkhf(ox, oy);
}

// ---------------- fused pooling + MLP: one block per graph, 1024 threads, packed-f16 input ----------------
// phase 1: (c2 = t&63, q = t>>6): 64 u32-cols x 16-deep rows; phase 2 MLP: (c = t&127, q = t>>7)
__global__ __launch_bounds__(1024) void pool_mlp(const unsigned* __restrict__ outh,
                                                 const int* __restrict__ batch,
                                                 const float* __restrict__ W,
                                                 const float* __restrict__ bm,
                                                 float* __restrict__ out) {
  __shared__ float pm0[16][64];
  __shared__ float pm1[16][64];
  __shared__ float p[128];
  __shared__ float acc8[8][128];
  int g = blockIdx.x, t = threadIdx.x;
  // lower bounds of g and g+1 in sorted batch_ids
  int a = 0, bnd = NN;
  while (a < bnd) { int m = (a + bnd) >> 1; if (batch[m] < g) a = m + 1; else bnd = m; }
  int lo = a;
  bnd = NN;
  while (a < bnd) { int m = (a + bnd) >> 1; if (batch[m] < g + 1) a = m + 1; else bnd = m; }
  int hi = a;
  int c2 = t & 63, q16 = t >> 6;      // 16-deep row groups
  float m0 = 0.f, m1 = 0.f;           // relu outputs >= 0
  for (int n = lo + q16; n < hi; n += 16) {
    hv2 v = __builtin_bit_cast(hv2, outh[(size_t)n * 64 + c2]);
    m0 = fmaxf(m0, (float)v.x);
    m1 = fmaxf(m1, (float)v.y);
  }
  pm0[q16][c2] = m0;
  pm1[q16][c2] = m1;
  __syncthreads();
  if (t < 64) {
    float r0 = pm0[0][t], r1 = pm1[0][t];
#pragma unroll
    for (int i = 1; i < 16; ++i) {
      r0 = fmaxf(r0, pm0[i][t]);
      r1 = fmaxf(r1, pm1[i][t]);
    }
    p[2 * t] = r0;
    p[2 * t + 1] = r1;
  }
  __syncthreads();
  // MLP: thread (c, q) partial-dots k = 16q .. 16q+15
  int c = t & 127, q = t >> 7;
  float acc = 0.f;
#pragma unroll
  for (int kk = 0; kk < 16; ++kk) {
    int k = q * 16 + kk;
    acc = fmaf(p[k], W[k * 128 + c], acc);
  }
  acc8[q][c] = acc;
  __syncthreads();
  if (q == 0) {
    float sum = bm[c];
#pragma unroll
    for (int i = 0; i < 8; ++i) sum += acc8[i][c];
    out[g * 128 + c] = fmaxf(sum, 0.f);
  }
}

extern "C" void kernel_launch(void* const* d_in, const int* in_sizes, int n_in,
                              void* d_out, int out_size, void* d_ws, size_t ws_size,
                              hipStream_t stream) {
  const float* x    = (const float*)d_in[0];
  const int*   ei   = (const int*)d_in[1];
  const int*   batch= (const int*)d_in[2];
  const float* Wl   = (const float*)d_in[4];
  const float* Wr   = (const float*)d_in[5];
  const float* att  = (const float*)d_in[6];
  const float* bias = (const float*)d_in[7];
  const float* Wm   = (const float*)d_in[8];
  const float* bm   = (const float*)d_in[9];

  char* ws = (char*)d_ws;
  size_t off = 0;
  auto alloc = [&](size_t bytes) { void* p = ws + off; off += (bytes + 255) & ~size_t(255); return p; };
  unsigned* xlu  = (unsigned*)alloc((size_t)NN * 64 * 4);   // f16-packed xl (12.8 MB)
  unsigned* xru  = (unsigned*)alloc((size_t)NN * 64 * 4);   // f16-packed xr (12.8 MB)
  unsigned* outh = (unsigned*)alloc((size_t)NN * 64 * 4);   // f16-packed conv output
  int*   rs      = (int*)alloc((size_t)(NN + 1) * 4);
  int*   csr     = (int*)alloc((size_t)(EE + NN) * 4);
  int*   H2T     = (int*)alloc((size_t)NTOT * 4);           // 800 KB bucket-major counts
  int*   PS      = (int*)alloc((size_t)NTOT * 4);           // 800 KB scanned positions
  int*   ec      = (int*)alloc((size_t)EE * 4);             // 3.2 MB coarse-sorted edges
  int*   bsum    = (int*)alloc(NSB * 4);
  short* Wtb     = (short*)alloc((size_t)256 * 128 * 2);    // bf16 W^T [col][k]

  prep_w<<<256, 128, 0, stream>>>(Wl, Wr, Wtb);
  gemm_xw<<<(NN + 127) / 128, 256, 0, stream>>>(x, Wtb, (_Float16*)xlu, (_Float16*)xru, ei, H2T);
  scanA<<<NSB, 256, 0, stream>>>(H2T, PS, bsum);
  scatter_coarse<<<NBLK, 512, 0, stream>>>(ei, PS, bsum, ec);
  fine_sort<<<NBUCK, 512, 0, stream>>>(PS, bsum, ec, rs, csr);
  gat_agg<<<NN / 4, 256, 0, stream>>>(xlu, xru, rs, csr, att, bias, outh);
  pool_mlp<<<GG, 1024, 0, stream>>>(outh, batch, Wm, bm, (float*)d_out);
}

// Round 20
// 127.181 us; speedup vs baseline: 1.1047x; 1.0085x over previous
//
#include <hip/hip_runtime.h>
#include <hip/hip_bf16.h>

#define NN 50000
#define EE 800000
#define HC 128
#define GG 64

#define NBLK 256
#define CHUNK (EE / NBLK)          // 3125
#define NBUCK ((NN + 63) >> 6)     // 782 coarse buckets (64 nodes each)
#define NTOT (NBUCK * NBLK)        // 200192 count-matrix entries
#define NSB ((NTOT + 1023) / 1024) // 196 scan blocks
#define ECAP 2048                  // per-bucket edge capacity (mean ~1023, sd ~32)

typedef __attribute__((ext_vector_type(8))) short bf16x8;
typedef __attribute__((ext_vector_type(4))) float f32x4;
typedef _Float16 hv2 __attribute__((ext_vector_type(2)));

// ---- DPP 16-lane rotate-reduction, FUSED form (old=0, bound_ctrl=1 -> v_add_f32_dpp):
// after ror by 1,2,4,8 every lane holds its 16-lane-row sum. No DS op, no lane-15 bottleneck.
__device__ __forceinline__ float dpp4_rorsum(float t) {
  t += __int_as_float(__builtin_amdgcn_update_dpp(0, __float_as_int(t), 0x121, 0xf, 0xf, true));
  t += __int_as_float(__builtin_amdgcn_update_dpp(0, __float_as_int(t), 0x122, 0xf, 0xf, true));
  t += __int_as_float(__builtin_amdgcn_update_dpp(0, __float_as_int(t), 0x124, 0xf, 0xf, true));
  t += __int_as_float(__builtin_amdgcn_update_dpp(0, __float_as_int(t), 0x128, 0xf, 0xf, true));
  return t;
}

__device__ __forceinline__ unsigned pkbf(float lo, float hi) {
  __hip_bfloat162 h = __float22bfloat162_rn(float2{lo, hi});  // x -> low 16 bits
  return *reinterpret_cast<unsigned*>(&h);
}
__device__ __forceinline__ unsigned pkhf(float lo, float hi) {
  hv2 h; h.x = (_Float16)lo; h.y = (_Float16)hi;
  return __builtin_bit_cast(unsigned, h);
}

// ---------------- W transpose+convert ----------------
__global__ __launch_bounds__(128) void prep_w(const float* __restrict__ Wl,
                                              const float* __restrict__ Wr,
                                              short* __restrict__ Wtb) {
  int c = blockIdx.x;           // 0..255
  int k = threadIdx.x;          // 0..127
  const float* W = (c < 128) ? Wl : Wr;
  float v = W[k * 128 + (c & 127)];
  Wtb[c * 128 + k] = (short)(pkbf(v, 0.f) & 0xFFFF);
}

// ---------------- GEMM (MFMA bf16) + fused coarse histogram ----------------
__global__ __launch_bounds__(256) void gemm_xw(
    const float* __restrict__ x, const short* __restrict__ Wtb,
    _Float16* __restrict__ xlh, _Float16* __restrict__ xrh,
    const int* __restrict__ ei, int* __restrict__ H2T)
{
  __shared__ short xs[128 * 136];
  __shared__ int h[NBUCK];
  const int t = threadIdx.x;
  const int rowbase = blockIdx.x * 128;
#pragma unroll
  for (int i = 0; i < 16; ++i) {
    int fi = i * 256 + t;            // 4096 float4 per tile
    int row = fi >> 5, k4 = fi & 31;
    int ar = rowbase + row; if (ar >= NN) ar = NN - 1;
    float4 v = *(const float4*)(x + (size_t)ar * 128 + k4 * 4);
    uint2 p = { pkbf(v.x, v.y), pkbf(v.z, v.w) };
    *(uint2*)&xs[row * 136 + k4 * 4] = p;
  }
  __syncthreads();
  const int w = t >> 6, l = t & 63;
  const int lo16 = l & 15, hi = l >> 4;
  f32x4 accL[2][8], accR[2][8];
#pragma unroll
  for (int rf = 0; rf < 2; ++rf)
#pragma unroll
    for (int cf = 0; cf < 8; ++cf) {
      accL[rf][cf] = f32x4{0.f, 0.f, 0.f, 0.f};
      accR[rf][cf] = f32x4{0.f, 0.f, 0.f, 0.f};
    }

  const short* asrc0 = &xs[(w * 32 + lo16) * 136 + hi * 8];
  const short* asrc1 = asrc0 + 16 * 136;
#pragma unroll
  for (int ks = 0; ks < 4; ++ks) {
    bf16x8 a0 = *(const bf16x8*)(asrc0 + ks * 32);
    bf16x8 a1 = *(const bf16x8*)(asrc1 + ks * 32);
#pragma unroll
    for (int cf = 0; cf < 8; ++cf) {
      const short* bp = &Wtb[(cf * 16 + lo16) * 128 + ks * 32 + hi * 8];
      bf16x8 bL = *(const bf16x8*)bp;
      bf16x8 bR = *(const bf16x8*)(bp + 128 * 128);
      accL[0][cf] = __builtin_amdgcn_mfma_f32_16x16x32_bf16(a0, bL, accL[0][cf], 0, 0, 0);
      accL[1][cf] = __builtin_amdgcn_mfma_f32_16x16x32_bf16(a1, bL, accL[1][cf], 0, 0, 0);
      accR[0][cf] = __builtin_amdgcn_mfma_f32_16x16x32_bf16(a0, bR, accR[0][cf], 0, 0, 0);
      accR[1][cf] = __builtin_amdgcn_mfma_f32_16x16x32_bf16(a1, bR, accR[1][cf], 0, 0, 0);
    }
  }
  // D layout: col=l&15, row=(l>>4)*4+reg
#pragma unroll
  for (int rf = 0; rf < 2; ++rf)
#pragma unroll
    for (int cf = 0; cf < 8; ++cf)
#pragma unroll
      for (int r = 0; r < 4; ++r) {
        int row = rowbase + w * 32 + rf * 16 + hi * 4 + r;
        if (row < NN) {
          int col = cf * 16 + lo16;
          xlh[(size_t)row * 128 + col] = (_Float16)accL[rf][cf][r];
          xrh[(size_t)row * 128 + col] = (_Float16)accR[rf][cf][r];
        }
      }
  // ---- fused histogram (blocks 0..NBLK-1) ----
  int blk = blockIdx.x;
  if (blk < NBLK) {
    for (int b = t; b < NBUCK; b += 256) h[b] = 0;
    __syncthreads();
    int e0 = blk * CHUNK;
    for (int i = t; i < CHUNK; i += 256) {
      int d = ei[EE + e0 + i];
      atomicAdd(&h[d >> 6], 1);      // LDS atomic
    }
    __syncthreads();
    for (int b = t; b < NBUCK; b += 256) H2T[b * NBLK + blk] = h[b];
  }
}

// K2: coalesced exclusive scan of the bucket-major count array; bsum[blk] = block total.
__global__ __launch_bounds__(256) void scanA(const int* __restrict__ H2T,
                                             int* __restrict__ PS, int* __restrict__ bsum) {
  __shared__ int tmp[256];
  int t = threadIdx.x;
  int base = blockIdx.x * 1024 + t * 4;
  int4 v = {0, 0, 0, 0};
  if (base < NTOT) v = *(const int4*)&H2T[base];   // NTOT % 4 == 0
  int local = v.x + v.y + v.z + v.w;
  tmp[t] = local; __syncthreads();
  for (int off = 1; off < 256; off <<= 1) {
    int xv = (t >= off) ? tmp[t - off] : 0; __syncthreads();
    tmp[t] += xv; __syncthreads();
  }
  int excl = tmp[t] - local;
  if (base < NTOT) {
    int4 o;
    o.x = excl; excl += v.x;
    o.y = excl; excl += v.y;
    o.z = excl; excl += v.z;
    o.w = excl;
    *(int4*)&PS[base] = o;
  }
  if (t == 255) bsum[blockIdx.x] = tmp[255];
}

// K3: scatter into per-(bucket,block) sequential runs; pack src|fine<<16 (inline bsum scan).
__global__ __launch_bounds__(512) void scatter_coarse(const int* __restrict__ ei,
                                                      const int* __restrict__ PS,
                                                      const int* __restrict__ bsum,
                                                      int* __restrict__ ec) {
  __shared__ int colbase[NBUCK];
  __shared__ int cur[NBUCK];
  __shared__ int sb[NSB];
  __shared__ int stmp[512];
  int t = threadIdx.x, blk = blockIdx.x;
  int v = (t < NSB) ? bsum[t] : 0;
  stmp[t] = v; __syncthreads();
  for (int off = 1; off < 512; off <<= 1) {
    int xv = (t >= off) ? stmp[t - off] : 0; __syncthreads();
    stmp[t] += xv; __syncthreads();
  }
  if (t < NSB) sb[t] = stmp[t] - v;
  __syncthreads();
  for (int b = t; b < NBUCK; b += 512) {
    int L = b * NBLK + blk;
    colbase[b] = PS[L] + sb[L >> 10];
    cur[b] = 0;
  }
  __syncthreads();
  int e0 = blk * CHUNK;
  for (int i = t; i < CHUNK; i += 512) {
    int d = ei[EE + e0 + i], s = ei[e0 + i];
    int b = d >> 6;
    int r = atomicAdd(&cur[b], 1);  // LDS atomic
    ec[colbase[b] + r] = s | ((d & 63) << 16);
  }
}

// K4: per-bucket fine sort, inject self-loops, emit rs + coalesced csr (inline bsum scan).
__global__ __launch_bounds__(512) void fine_sort(const int* __restrict__ PS,
                                                 const int* __restrict__ bsum,
                                                 const int* __restrict__ ec,
                                                 int* __restrict__ rs, int* __restrict__ csr) {
  __shared__ int lbuf[ECAP];
  __shared__ int outb[ECAP + 64];
  __shared__ int fh[64], sexcl[65], cur2[64];
  __shared__ int sb[NSB];
  __shared__ int stmp[512];
  int t = threadIdx.x, b = blockIdx.x;
  int v = (t < NSB) ? bsum[t] : 0;
  stmp[t] = v; __syncthreads();
  for (int off = 1; off < 512; off <<= 1) {
    int xv = (t >= off) ? stmp[t - off] : 0; __syncthreads();
    stmp[t] += xv; __syncthreads();
  }
  if (t < NSB) sb[t] = stmp[t] - v;
  __syncthreads();
  int L0 = b * NBLK;
  int start = PS[L0] + sb[L0 >> 10];
  int end = (b + 1 < NBUCK) ? PS[L0 + NBLK] + sb[(L0 + NBLK) >> 10] : EE;
  int node0 = b << 6;
  int nl = NN - node0; if (nl > 64) nl = 64;
  int cnt = end - start; if (cnt > ECAP) cnt = ECAP;
  if (t < 64) { fh[t] = 0; cur2[t] = 0; }
  __syncthreads();
  for (int i = t; i < cnt; i += 512) {
    int p = ec[start + i];
    lbuf[i] = p;
    atomicAdd(&fh[(p >> 16) & 63], 1);
  }
  __syncthreads();
  if (t < 64) {   // wave 0: inclusive shfl-scan of 64 bins (+1 self-loop per live node)
    int val = fh[t] + (t < nl ? 1 : 0);
    int w = val;
    for (int off = 1; off < 64; off <<= 1) {
      int u = __shfl_up(w, off);
      if (t >= off) w += u;
    }
    sexcl[t] = w - val;
    if (t == 63) sexcl[64] = w;
  }
  __syncthreads();
  int base = start + node0;   // node0 == number of self-loops in earlier buckets
  if (t <= nl) rs[node0 + t] = base + sexcl[t];
  if (t < nl) {
    int r = atomicAdd(&cur2[t], 1);
    outb[sexcl[t] + r] = node0 + t;              // self-loop src = node itself
  }
  for (int i = t; i < cnt; i += 512) {
    int p = lbuf[i];
    int f = (p >> 16) & 63;
    int r = atomicAdd(&cur2[f], 1);
    outb[sexcl[f] + r] = p & 0xFFFF;             // src < 65536 (NN = 50000)
  }
  __syncthreads();
  int tot = cnt + nl;
  for (int i = t; i < tot; i += 512) csr[base + i] = outb[i];
}

// process M staged edges (stage-split: logits, exps, accumulate); DPP-only reduction
template<int M>
__device__ __forceinline__ void procM(const unsigned* wv, hv2 att2, hv2 xr2,
                                      float& s, float& a0, float& a1) {
  float tb[M];
#pragma unroll
  for (int i = 0; i < M; ++i) {
    hv2 v = __builtin_bit_cast(hv2, wv[i]);
    hv2 y = v + xr2;
    hv2 lr = __builtin_elementwise_max(y, y * (_Float16)0.2f);
    float td = __builtin_amdgcn_fdot2(lr, att2, 0.f, false);
    tb[i] = dpp4_rorsum(td);
  }
  float p[M];
#pragma unroll
  for (int i = 0; i < M; ++i) p[i] = __builtin_amdgcn_exp2f(tb[i]);
#pragma unroll
  for (int i = 0; i < M; ++i) {
    hv2 v = __builtin_bit_cast(hv2, wv[i]);
    s += p[i];
    a0 = fmaf(p[i], (float)v.x, a0);
    a1 = fmaf(p[i], (float)v.y, a1);
  }
}

// ---------------- main aggregation: one wave per node, 2-deep pipelined 8-edge batches ----------------
__global__ __launch_bounds__(256) void gat_agg(
    const unsigned* __restrict__ xlu, const unsigned* __restrict__ xru,
    const int* __restrict__ rs, const int* __restrict__ csr,
    const float* __restrict__ att, const float* __restrict__ bias,
    unsigned* __restrict__ outh)
{
  int wid = threadIdx.x >> 6, lane = threadIdx.x & 63;
  int n = blockIdx.x * 4 + wid;
  if (n >= NN) return;
  hv2 xr2 = __builtin_bit_cast(hv2, xru[n * 64 + lane]);
  float2 at2 = ((const float2*)att)[lane];
  const float LOG2E = 1.4426950408889634f;
  hv2 att2;
  att2.x = (_Float16)(at2.x * LOG2E);
  att2.y = (_Float16)(at2.y * LOG2E);
  float s = 0.f, a0 = 0.f, a1 = 0.f;

  int jbeg = rs[n], jend = rs[n + 1];
  for (int j0 = jbeg; j0 < jend; j0 += 64) {
    int cnt = jend - j0; if (cnt > 64) cnt = 64;
    int sj = csr[j0 + (lane < cnt ? lane : cnt - 1)];
    int base = 0;
    if (cnt >= 8) {
      unsigned cur[8];
#pragma unroll
      for (int i = 0; i < 8; ++i)
        cur[i] = xlu[__builtin_amdgcn_readlane(sj, i) * 64 + lane];
      for (; base + 16 <= cnt; base += 8) {
        unsigned nxt[8];
#pragma unroll
        for (int i = 0; i < 8; ++i)   // prefetch batch k+1 before computing batch k
          nxt[i] = xlu[__builtin_amdgcn_readlane(sj, base + 8 + i) * 64 + lane];
        procM<8>(cur, att2, xr2, s, a0, a1);
#pragma unroll
        for (int i = 0; i < 8; ++i) cur[i] = nxt[i];
      }
      procM<8>(cur, att2, xr2, s, a0, a1);
      base += 8;
    }
    int rem = cnt - base;   // 0..7, wave-uniform
    if (rem) {
      unsigned wv[8];
#pragma unroll
      for (int i = 0; i < 8; ++i)
        if (i < rem) wv[i] = xlu[__builtin_amdgcn_readlane(sj, base + i) * 64 + lane];
      switch (rem) {
        case 1: procM<1>(wv, att2, xr2, s, a0, a1); break;
        case 2: procM<2>(wv, att2, xr2, s, a0, a1); break;
        case 3: procM<3>(wv, att2, xr2, s, a0, a1); break;
        case 4: procM<4>(wv, att2, xr2, s, a0, a1); break;
        case 5: procM<5>(wv, att2, xr2, s, a0, a1); break;
        case 6: procM<6>(wv, att2, xr2, s, a0, a1); break;
        default: procM<7>(wv, att2, xr2, s, a0, a1); break;
      }
    }
  }
  float inv = 1.f / s;
  float2 bi = ((const float2*)bias)[lane];
  float ox = fmaxf(fmaf(a0, inv, bi.x), 0.f);
  float oy = fmaxf(fmaf(a1, inv, bi.y), 0.f);
  outh[(size_t)n * 64 + lane] = pkhf(ox, oy);
}

// ---------------- fused pooling + MLP: one block per graph, 1024 threads, packed-f16 input ----------------
__global__ __launch_bounds__(1024) void pool_mlp(const unsigned* __restrict__ outh,
                                                 const int* __restrict__ batch,
                                                 const float* __restrict__ W,
                                                 const float* __restrict__ bm,
                                                 float* __restrict__ out) {
  __shared__ float pm0[16][64];
  __shared__ float pm1[16][64];
  __shared__ float p[128];
  __shared__ float acc8[8][128];
  int g = blockIdx.x, t = threadIdx.x;
  int a = 0, bnd = NN;
  while (a < bnd) { int m = (a + bnd) >> 1; if (batch[m] < g) a = m + 1; else bnd = m; }
  int lo = a;
  bnd = NN;
  while (a < bnd) { int m = (a + bnd) >> 1; if (batch[m] < g + 1) a = m + 1; else bnd = m; }
  int hi = a;
  int c2 = t & 63, q16 = t >> 6;      // 16-deep row groups
  float m0 = 0.f, m1 = 0.f;           // relu outputs >= 0
  for (int n = lo + q16; n < hi; n += 16) {
    hv2 v = __builtin_bit_cast(hv2, outh[(size_t)n * 64 + c2]);
    m0 = fmaxf(m0, (float)v.x);
    m1 = fmaxf(m1, (float)v.y);
  }
  pm0[q16][c2] = m0;
  pm1[q16][c2] = m1;
  __syncthreads();
  if (t < 64) {
    float r0 = pm0[0][t], r1 = pm1[0][t];
#pragma unroll
    for (int i = 1; i < 16; ++i) {
      r0 = fmaxf(r0, pm0[i][t]);
      r1 = fmaxf(r1, pm1[i][t]);
    }
    p[2 * t] = r0;
    p[2 * t + 1] = r1;
  }
  __syncthreads();
  int c = t & 127, q = t >> 7;
  float acc = 0.f;
#pragma unroll
  for (int kk = 0; kk < 16; ++kk) {
    int k = q * 16 + kk;
    acc = fmaf(p[k], W[k * 128 + c], acc);
  }
  acc8[q][c] = acc;
  __syncthreads();
  if (q == 0) {
    float sum = bm[c];
#pragma unroll
    for (int i = 0; i < 8; ++i) sum += acc8[i][c];
    out[g * 128 + c] = fmaxf(sum, 0.f);
  }
}

extern "C" void kernel_launch(void* const* d_in, const int* in_sizes, int n_in,
                              void* d_out, int out_size, void* d_ws, size_t ws_size,
                              hipStream_t stream) {
  const float* x    = (const float*)d_in[0];
  const int*   ei   = (const int*)d_in[1];
  const int*   batch= (const int*)d_in[2];
  const float* Wl   = (const float*)d_in[4];
  const float* Wr   = (const float*)d_in[5];
  const float* att  = (const float*)d_in[6];
  const float* bias = (const float*)d_in[7];
  const float* Wm   = (const float*)d_in[8];
  const float* bm   = (const float*)d_in[9];

  char* ws = (char*)d_ws;
  size_t off = 0;
  auto alloc = [&](size_t bytes) { void* p = ws + off; off += (bytes + 255) & ~size_t(255); return p; };
  unsigned* xlu  = (unsigned*)alloc((size_t)NN * 64 * 4);   // f16-packed xl (12.8 MB)
  unsigned* xru  = (unsigned*)alloc((size_t)NN * 64 * 4);   // f16-packed xr (12.8 MB)
  unsigned* outh = (unsigned*)alloc((size_t)NN * 64 * 4);   // f16-packed conv output
  int*   rs      = (int*)alloc((size_t)(NN + 1) * 4);
  int*   csr     = (int*)alloc((size_t)(EE + NN) * 4);
  int*   H2T     = (int*)alloc((size_t)NTOT * 4);           // 800 KB bucket-major counts
  int*   PS      = (int*)alloc((size_t)NTOT * 4);           // 800 KB scanned positions
  int*   ec      = (int*)alloc((size_t)EE * 4);             // 3.2 MB coarse-sorted edges
  int*   bsum    = (int*)alloc(NSB * 4);
  short* Wtb     = (short*)alloc((size_t)256 * 128 * 2);    // bf16 W^T [col][k]

  prep_w<<<256, 128, 0, stream>>>(Wl, Wr, Wtb);
  gemm_xw<<<(NN + 127) / 128, 256, 0, stream>>>(x, Wtb, (_Float16*)xlu, (_Float16*)xru, ei, H2T);
  scanA<<<NSB, 256, 0, stream>>>(H2T, PS, bsum);
  scatter_coarse<<<NBLK, 512, 0, stream>>>(ei, PS, bsum, ec);
  fine_sort<<<NBUCK, 512, 0, stream>>>(PS, bsum, ec, rs, csr);
  gat_agg<<<NN / 4, 256, 0, stream>>>(xlu, xru, rs, csr, att, bias, outh);
  pool_mlp<<<GG, 1024, 0, stream>>>(outh, batch, Wm, bm, (float*)d_out);
}